// Round 15
// baseline (121.746 us; speedup 1.0000x reference)
//
#include <hip/hip_runtime.h>

#pragma clang fp contract(off)

#define A_TOTAL 65472
#define NB 16
#define NG 32

// One kernel. Wave = 256 anchors (4/lane in registers), block = 4 waves.
// 64 blocks per image, grid = 1024. Range r==255 has only 192 anchors.
// part2[b][g] u64 key = (iou_bits<<32) | ~n : atomicMax gives max-iou,
// tie -> smallest global n == (first max level, first in-level argmax).
// Last finishing block performs the forced-anchor overwrite (last-g-wins).

__global__ __launch_bounds__(256) void fused_kernel(
    const float* __restrict__ bb,       // [NB][NG][4]
    const int* __restrict__ ids,        // [NB][NG]
    const float* __restrict__ anchors,  // [A_TOTAL][4]
    unsigned long long* __restrict__ part2, // [NB*NG], pre-zeroed
    unsigned int* __restrict__ counter,     // pre-zeroed
    float* __restrict__ out)            // labels [NB*A] then regs [NB*A*4]
{
    const int wid  = threadIdx.x >> 6;
    const int lane = threadIdx.x & 63;
    const int b = blockIdx.x >> 6;                  // 64 blocks per image
    const int r = ((blockIdx.x & 63) << 2) + wid;   // 256-anchor range, 0..255
    const int start = r << 8;
    const bool full = (r != 255);

    __shared__ float4 sbb[NG];
    __shared__ float  sag[NG];
    __shared__ int    sid[NG];
    if (threadIdx.x < NG) {
        float4 q = ((const float4*)bb)[b * NG + threadIdx.x];
        sbb[threadIdx.x] = q;
        sag[threadIdx.x] = (q.z - q.x) * (q.w - q.y);
        sid[threadIdx.x] = ids[b * NG + threadIdx.x];
    }
    __syncthreads();

    // 4 anchors per lane in registers
    float4 an[4];
    float  aa[4];
#pragma unroll
    for (int k = 0; k < 4; ++k) {
        if (k == 3 && !full) { an[3] = an[0]; aa[3] = aa[0]; continue; }
        an[k] = ((const float4*)anchors)[start + (k << 6) + lane];
        aa[k] = (an[k].z - an[k].x) * (an[k].w - an[k].y);
    }

    float abest[4] = {-1.0f, -1.0f, -1.0f, -1.0f};
    int   agid[4]  = {0, 0, 0, 0};
    unsigned long long red = 0ull;      // lane<32: reduced key for g==lane

    for (int j = 0; j < 16; ++j) {      // g-pairs (g0=2j, g1=2j+1)
        const int g0 = j << 1;
        const int g1 = g0 + 1;
        const float4 q0 = sbb[g0]; const float ag0 = sag[g0];
        const float4 q1 = sbb[g1]; const float ag1 = sag[g1];

        float v0 = -1.0f, v1 = -1.0f;
        unsigned int n0 = 0u, n1 = 0u;
#pragma unroll
        for (int k = 0; k < 4; ++k) {
            if (k == 3 && !full) continue;          // wave-uniform
            const unsigned int n = (unsigned int)(start + (k << 6) + lane);
            {   // g0
                float x1 = fmaxf(an[k].x, q0.x);
                float y1 = fmaxf(an[k].y, q0.y);
                float x2 = fminf(an[k].z, q0.z);
                float y2 = fminf(an[k].w, q0.w);
                float ww = fmaxf(x2 - x1, 0.0f);
                float hh = fmaxf(y2 - y1, 0.0f);
                float inter = ww * hh;
                float denom = aa[k] + ag0 - inter + 1e-9f;
                float v = inter / denom;
                if (v > v0) { v0 = v; n0 = n; }                 // ascending n
                if (v > abest[k]) { abest[k] = v; agid[k] = g0; } // ascending g
            }
            {   // g1
                float x1 = fmaxf(an[k].x, q1.x);
                float y1 = fmaxf(an[k].y, q1.y);
                float x2 = fminf(an[k].z, q1.z);
                float y2 = fminf(an[k].w, q1.w);
                float ww = fmaxf(x2 - x1, 0.0f);
                float hh = fmaxf(y2 - y1, 0.0f);
                float inter = ww * hh;
                float denom = aa[k] + ag1 - inter + 1e-9f;
                float v = inter / denom;
                if (v > v1) { v1 = v; n1 = n; }
                if (v > abest[k]) { abest[k] = v; agid[k] = g1; }
            }
        }
        // paired-g reduction: lanes<32 reduce g0, lanes>=32 reduce g1
        unsigned long long k0 =
            ((unsigned long long)__float_as_uint(v0) << 32) | (unsigned long long)(~n0);
        unsigned long long k1 =
            ((unsigned long long)__float_as_uint(v1) << 32) | (unsigned long long)(~n1);
        unsigned long long x = (lane < 32) ? k0 : k1;
        unsigned long long y = __shfl_xor((lane < 32) ? k1 : k0, 32, 64);
        if (y > x) x = y;
#pragma unroll
        for (int s = 1; s < 32; s <<= 1) {
            unsigned long long o = __shfl_xor(x, s, 64);
            if (o > x) x = o;
        }
        unsigned long long y2 = __shfl_xor(x, 32, 64);  // other half's result
        if (lane == g0) red = x;    // lanes<32 hold g0 max
        if (lane == g1) red = y2;   // lanes<32: y2 = g1 max
    }
    if (lane < NG) {
        atomicMax(&part2[b * NG + lane], red);
    }

    // per-anchor outputs
#pragma unroll
    for (int k = 0; k < 4; ++k) {
        if (k == 3 && !full) continue;
        const int n = start + (k << 6) + lane;
        float label;
        float4 rg;
        if (abest[k] >= 0.5f) {
            const float4 gtb = sbb[agid[k]];
            label = (float)sid[agid[k]];
            float aw = an[k].z - an[k].x;
            float ah = an[k].w - an[k].y;
            float ax = an[k].x + 0.5f * aw;
            float ay = an[k].y + 0.5f * ah;
            float gw = gtb.z - gtb.x;
            float gh = gtb.w - gtb.y;
            float gx = gtb.x + 0.5f * gw;
            float gy = gtb.y + 0.5f * gh;
            rg = make_float4((gx - ax) / aw, (gy - ay) / ah, logf(gw / aw), logf(gh / ah));
        } else {
            label = (abest[k] >= 0.4f) ? -1.0f : 0.0f;
            rg = make_float4(0.0f, 0.0f, 0.0f, 0.0f);
        }
        out[b * A_TOTAL + n] = label;
        ((float4*)(out + NB * A_TOTAL))[b * A_TOTAL + n] = rg;
    }

    // ---- last-block tail: forced-anchor overwrite ----
    __shared__ int sdone;
    __syncthreads();
    if (threadIdx.x == 0) {
        __threadfence();    // release: epilogue stores + atomics visible device-wide
        sdone = (atomicAdd(counter, 1u) == (unsigned int)(gridDim.x - 1)) ? 1 : 0;
    }
    __syncthreads();
    if (!sdone) return;

    __shared__ int sfor[NB * NG];
    for (int t = threadIdx.x; t < NB * NG; t += 256) {
        unsigned long long kk = atomicMax(&part2[t], 0ull);  // coherent read
        sfor[t] = (int)(~(unsigned int)(kk & 0xFFFFFFFFull));
    }
    __syncthreads();
    for (int t = threadIdx.x; t < NB * NG; t += 256) {
        const int bi = t >> 5;
        const int g  = t & 31;
        const int n  = sfor[t];
        bool shadowed = false;
        for (int g2 = g + 1; g2 < NG; ++g2)
            if (sfor[(bi << 5) | g2] == n) shadowed = true;   // last g wins
        if (!shadowed) {
            const float4 gtb = ((const float4*)bb)[t];
            const float4 a   = ((const float4*)anchors)[n];
            float aw = a.z - a.x;
            float ah = a.w - a.y;
            float ax = a.x + 0.5f * aw;
            float ay = a.y + 0.5f * ah;
            float gw = gtb.z - gtb.x;
            float gh = gtb.w - gtb.y;
            float gx = gtb.x + 0.5f * gw;
            float gy = gtb.y + 0.5f * gh;
            out[bi * A_TOTAL + n] = (float)ids[t];
            ((float4*)(out + NB * A_TOTAL))[bi * A_TOTAL + n] =
                make_float4((gx - ax) / aw, (gy - ay) / ah, logf(gw / aw), logf(gh / ah));
        }
    }
}

extern "C" void kernel_launch(void* const* d_in, const int* in_sizes, int n_in,
                              void* d_out, int out_size, void* d_ws, size_t ws_size,
                              hipStream_t stream) {
    const float* bb      = (const float*)d_in[0];
    const int*   ids     = (const int*)d_in[1];
    const float* anchors = (const float*)d_in[2];
    float* out = (float*)d_out;

    unsigned long long* part2 = (unsigned long long*)d_ws;              // 4096 B
    unsigned int* counter = (unsigned int*)((char*)d_ws + NB * NG * 8); // 4 B

    hipMemsetAsync(d_ws, 0, NB * NG * 8 + 64, stream);
    hipLaunchKernelGGL(fused_kernel, dim3(NB * 64), dim3(256), 0, stream,
                       bb, ids, anchors, part2, counter, out);
}